// Round 2
// baseline (394.409 us; speedup 1.0000x reference)
//
#include <hip/hip_runtime.h>
#include <hip/hip_bf16.h>

#define DDIM 2048
#define TTIMES 256
#define NT 64                 // K-steps of 32

typedef __attribute__((ext_vector_type(8))) short short8;
typedef __attribute__((ext_vector_type(4))) float f32x4;

__device__ __forceinline__ ushort f2bf(float f) {
    union { float f; unsigned int u; } v; v.f = f;
    unsigned int u = v.u;
    unsigned int r = (u + 0x7FFFu + ((u >> 16) & 1u)) >> 16;   // RNE
    return (ushort)r;
}
__device__ __forceinline__ float bf2f(ushort u) {
    union { unsigned int u; float f; } v; v.u = ((unsigned int)u) << 16;
    return v.f;
}
__device__ __forceinline__ short cvt1(float f) {
    union { __hip_bfloat16 h; ushort u; } cv;
    cv.h = __float2bfloat16(f);          // hardware RNE cvt
    return (short)cv.u;
}

// ---------------- normalize org rows -> bf16 o in workspace ----------------
__global__ void norm_rows(const float* __restrict__ org, ushort* __restrict__ obf) {
    const int a   = blockIdx.x;     // time row
    const int tid = threadIdx.x;    // 256 threads
    const float* row = org + (size_t)a * DDIM;
    float4 v0 = ((const float4*)row)[tid * 2];
    float4 v1 = ((const float4*)row)[tid * 2 + 1];
    float s = v0.x*v0.x + v0.y*v0.y + v0.z*v0.z + v0.w*v0.w
            + v1.x*v1.x + v1.y*v1.y + v1.z*v1.z + v1.w*v1.w;
    #pragma unroll
    for (int off = 1; off < 64; off <<= 1) s += __shfl_xor(s, off);
    __shared__ float wsum[4];
    const int lane = tid & 63, w = tid >> 6;
    if (lane == 0) wsum[w] = s;
    __syncthreads();
    const float tot = wsum[0] + wsum[1] + wsum[2] + wsum[3];
    const float scale = 1.0f / fmaxf(sqrtf(tot), 1e-12f);
    union { ushort u[8]; uint4 v; } pk;
    pk.u[0] = f2bf(v0.x * scale); pk.u[1] = f2bf(v0.y * scale);
    pk.u[2] = f2bf(v0.z * scale); pk.u[3] = f2bf(v0.w * scale);
    pk.u[4] = f2bf(v1.x * scale); pk.u[5] = f2bf(v1.y * scale);
    pk.u[6] = f2bf(v1.z * scale); pk.u[7] = f2bf(v1.w * scale);
    ((uint4*)(obf + (size_t)a * DDIM))[tid] = pk.v;
}

// ------------- barrier-free direct-from-global GEMM + trace reduce -------------
// Block: 256 threads = 4 waves. Block tile: 64 rows x 256 times.
// Wave wn owns times [wn*64, wn*64+64); all 4 waves read the same 64 A-rows
// (8 KB/step tile -> L1/L2 absorbs the duplication; HBM sees x once).
__global__ __launch_bounds__(256, 3) void gemm_trace(
    const float* __restrict__ x, const ushort* __restrict__ obf,
    float* __restrict__ part)
{
    const int tid  = threadIdx.x;
    const int lane = tid & 63;
    const int wn   = tid >> 6;          // 0..3 (time block)
    const int rb   = blockIdx.x;        // 0..31 (row block of 64)
    const int d    = blockIdx.y;        // 0..31 (batch)

    const int lr = lane & 15;           // row-in-16 (A) / time-in-16 (B)
    const int lq = lane >> 4;           // k-quarter (8 elems each)

    const float*  ap = x + (size_t)d * DDIM * DDIM
                         + (size_t)(rb * 64 + lr) * DDIM + lq * 8;
    const ushort* bp = obf + (size_t)(wn * 64 + lr) * DDIM + lq * 8;

    f32x4 acc[4][4];
    #pragma unroll
    for (int mi = 0; mi < 4; ++mi)
        #pragma unroll
        for (int ni = 0; ni < 4; ++ni)
            acc[mi][ni] = (f32x4){0.f, 0.f, 0.f, 0.f};

#define LOADT(AS, BS, t) do {                                               \
    _Pragma("unroll")                                                       \
    for (int mi = 0; mi < 4; ++mi) {                                        \
        const float* p_ = ap + (size_t)mi * 16 * DDIM + (t) * 32;           \
        AS[mi][0] = *(const float4*)p_;                                     \
        AS[mi][1] = *(const float4*)(p_ + 4);                               \
    }                                                                       \
    _Pragma("unroll")                                                       \
    for (int ni = 0; ni < 4; ++ni)                                          \
        BS[ni] = *(const uint4*)(bp + (size_t)ni * 16 * DDIM + (t) * 32);   \
} while (0)

#define CMPT(AS, BS) do {                                                   \
    _Pragma("unroll")                                                       \
    for (int mi = 0; mi < 4; ++mi) {                                        \
        short8 af_;                                                         \
        af_[0] = cvt1(AS[mi][0].x); af_[1] = cvt1(AS[mi][0].y);             \
        af_[2] = cvt1(AS[mi][0].z); af_[3] = cvt1(AS[mi][0].w);             \
        af_[4] = cvt1(AS[mi][1].x); af_[5] = cvt1(AS[mi][1].y);             \
        af_[6] = cvt1(AS[mi][1].z); af_[7] = cvt1(AS[mi][1].w);             \
        _Pragma("unroll")                                                   \
        for (int ni = 0; ni < 4; ++ni)                                      \
            acc[mi][ni] = __builtin_amdgcn_mfma_f32_16x16x32_bf16(          \
                af_, *(const short8*)&BS[ni], acc[mi][ni], 0, 0, 0);        \
    }                                                                       \
} while (0)

    float4 aA[4][2], aB[4][2];
    uint4  bA[4],   bB[4];

    LOADT(aA, bA, 0);
    for (int t = 0; t < NT; t += 2) {
        LOADT(aB, bB, t + 1);          // in flight under compute of set A
        CMPT(aA, bA);
        if (t + 2 < NT) LOADT(aA, bA, t + 2);
        CMPT(aB, bB);
    }
#undef LOADT
#undef CMPT

    // ---- fused trace epilogue: weight acc by o[a][row], reduce over rows ----
    // acc[mi][ni][j]: row = rb*64 + mi*16 + lq*4 + j,  time a = wn*64 + ni*16 + lr
    #pragma unroll
    for (int ni = 0; ni < 4; ++ni) {
        const int a_idx = wn * 64 + ni * 16 + lr;
        float ps = 0.f;
        #pragma unroll
        for (int mi = 0; mi < 4; ++mi) {
            const int bg = rb * 64 + mi * 16 + lq * 4;
            const ushort4 w = *(const ushort4*)(obf + (size_t)a_idx * DDIM + bg);
            ps += bf2f(w.x) * acc[mi][ni][0];
            ps += bf2f(w.y) * acc[mi][ni][1];
            ps += bf2f(w.z) * acc[mi][ni][2];
            ps += bf2f(w.w) * acc[mi][ni][3];
        }
        ps += __shfl_xor(ps, 16);
        ps += __shfl_xor(ps, 32);
        if (lane < 16)
            part[((size_t)d * 32 + rb) * TTIMES + a_idx] = ps;
    }
}

// ---------------- final reduce over row-blocks ----------------
__global__ void reduce_part(const float* __restrict__ part, float* __restrict__ out) {
    const int d = blockIdx.x;    // 32
    const int a = threadIdx.x;   // 256
    float s = 0.f;
    #pragma unroll
    for (int rb = 0; rb < 32; ++rb)
        s += part[((size_t)d * 32 + rb) * TTIMES + a];
    out[(size_t)d * TTIMES + a] = s;
}

extern "C" void kernel_launch(void* const* d_in, const int* in_sizes, int n_in,
                              void* d_out, int out_size, void* d_ws, size_t ws_size,
                              hipStream_t stream) {
    const float* x   = (const float*)d_in[0];   // (32, 2048, 2048) fp32
    const float* org = (const float*)d_in[1];   // (256, 2048) fp32
    float* out = (float*)d_out;                 // (32, 256) fp32

    ushort* obf = (ushort*)d_ws;                          // 1 MiB bf16 normalized o
    float*  prt = (float*)((char*)d_ws + (1 << 20));      // 1 MiB partials (32x32x256)

    norm_rows<<<dim3(TTIMES), dim3(256), 0, stream>>>(org, obf);
    gemm_trace<<<dim3(32, 32), dim3(256), 0, stream>>>(x, obf, prt);
    reduce_part<<<dim3(32), dim3(256), 0, stream>>>(prt, out);
}

// Round 3
// 151.543 us; speedup vs baseline: 2.6026x; 2.6026x over previous
//
#include <hip/hip_runtime.h>
#include <hip/hip_bf16.h>

#define DDIM 2048
#define TTIMES 256
#define NT 64                 // K-steps of 32
#define THREADS 512

typedef __attribute__((ext_vector_type(8))) short short8;
typedef __attribute__((ext_vector_type(4))) float f32x4;

using gvoid = const __attribute__((address_space(1))) void;
using svoid = __attribute__((address_space(3))) void;

__device__ __forceinline__ void gld16(const void* g, void* l) {
    __builtin_amdgcn_global_load_lds((gvoid*)g, (svoid*)l, 16, 0, 0);
}

__device__ __forceinline__ ushort f2bf(float f) {
    union { float f; unsigned int u; } v; v.f = f;
    unsigned int u = v.u;
    unsigned int r = (u + 0x7FFFu + ((u >> 16) & 1u)) >> 16;   // RNE
    return (ushort)r;
}
__device__ __forceinline__ float bf2f(ushort u) {
    union { unsigned int u; float f; } v; v.u = ((unsigned int)u) << 16;
    return v.f;
}
__device__ __forceinline__ short cvt1(float f) {
    union { __hip_bfloat16 h; ushort u; } cv;
    cv.h = __float2bfloat16(f);          // hardware RNE cvt
    return (short)cv.u;
}

// ---------------- normalize org rows -> bf16 o in workspace ----------------
__global__ void norm_rows(const float* __restrict__ org, ushort* __restrict__ obf) {
    const int a   = blockIdx.x;     // time row
    const int tid = threadIdx.x;    // 256 threads
    const float* row = org + (size_t)a * DDIM;
    float4 v0 = ((const float4*)row)[tid * 2];
    float4 v1 = ((const float4*)row)[tid * 2 + 1];
    float s = v0.x*v0.x + v0.y*v0.y + v0.z*v0.z + v0.w*v0.w
            + v1.x*v1.x + v1.y*v1.y + v1.z*v1.z + v1.w*v1.w;
    #pragma unroll
    for (int off = 1; off < 64; off <<= 1) s += __shfl_xor(s, off);
    __shared__ float wsum[4];
    const int lane = tid & 63, w = tid >> 6;
    if (lane == 0) wsum[w] = s;
    __syncthreads();
    const float tot = wsum[0] + wsum[1] + wsum[2] + wsum[3];
    const float scale = 1.0f / fmaxf(sqrtf(tot), 1e-12f);
    union { ushort u[8]; uint4 v; } pk;
    pk.u[0] = f2bf(v0.x * scale); pk.u[1] = f2bf(v0.y * scale);
    pk.u[2] = f2bf(v0.z * scale); pk.u[3] = f2bf(v0.w * scale);
    pk.u[4] = f2bf(v1.x * scale); pk.u[5] = f2bf(v1.y * scale);
    pk.u[6] = f2bf(v1.z * scale); pk.u[7] = f2bf(v1.w * scale);
    ((uint4*)(obf + (size_t)a * DDIM))[tid] = pk.v;
}

// ---- gload_lds double-buffered GEMM + fused trace, counted vmcnt ----
// Block: 512 thr = 8 waves (2 wm x 4 wn). Tile: 128 rows x 256 times x BK=32.
// A staged as raw fp32 (16 KB/step), B bf16 (16 KB/step). LDS 64 KB -> 2 blk/CU.
// XOR source-pre-swizzle (A: cq^=row&7, B: cq^=row&3) so fragment ds_reads
// don't bank-conflict; gload_lds dest stays linear (lane-contiguous).
__global__ __launch_bounds__(THREADS, 4) void gemm_trace(
    const float* __restrict__ x, const ushort* __restrict__ obf,
    float* __restrict__ part)
{
    __shared__ __align__(16) char Ab[2][16384];
    __shared__ __align__(16) char Bb[2][16384];

    const int tid  = threadIdx.x;
    const int lane = tid & 63;
    const int wid  = tid >> 6;      // 0..7
    const int wm   = wid >> 2;      // 0..1 (row half)
    const int wn   = wid & 3;       // 0..3 (time quarter)
    const int rb   = blockIdx.x;    // 0..15 (row block of 128)
    const int d    = blockIdx.y;    // 0..31 (batch)

    const char* ab = (const char*)(x + (size_t)d * DDIM * DDIM + (size_t)rb * 128 * DDIM);
    const char* bb = (const char*)obf;

    // staging: A 1024 chunks (128 rows x 8), B 1024 chunks (256 rows x 4); 2 each/thread
    const int ar0 = tid >> 3,         aq0 = ((tid & 7) ^ (ar0 & 7)) * 16;
    const int ar1 = (tid + 512) >> 3, aq1 = (((tid + 512) & 7) ^ (ar1 & 7)) * 16;
    const int br0 = tid >> 2,         bq0 = ((tid & 3) ^ (br0 & 3)) * 16;
    const int br1 = (tid + 512) >> 2, bq1 = (((tid + 512) & 3) ^ (br1 & 3)) * 16;

    const char* as0 = ab + (size_t)ar0 * (DDIM * 4) + aq0;
    const char* as1 = ab + (size_t)ar1 * (DDIM * 4) + aq1;
    const char* bs0 = bb + (size_t)br0 * (DDIM * 2) + bq0;
    const char* bs1 = bb + (size_t)br1 * (DDIM * 2) + bq1;

#define STAGE(t, buf) do {                                \
    gld16(as0 + (t) * 128, &Ab[buf][tid * 16]);           \
    gld16(as1 + (t) * 128, &Ab[buf][(tid + 512) * 16]);   \
    gld16(bs0 + (t) * 64,  &Bb[buf][tid * 16]);           \
    gld16(bs1 + (t) * 64,  &Bb[buf][(tid + 512) * 16]);   \
} while (0)

    const int lr = lane & 15;       // row-in-16 (A) / time-in-16 (B)
    const int lq = lane >> 4;       // k-quarter

    int aoff0[4], aoff1[4], boff[4];
    #pragma unroll
    for (int mi = 0; mi < 4; ++mi) {
        const int r = wm * 64 + mi * 16 + lr;
        aoff0[mi] = r * 128 + ((2 * lq)     ^ (r & 7)) * 16;
        aoff1[mi] = r * 128 + ((2 * lq + 1) ^ (r & 7)) * 16;
    }
    #pragma unroll
    for (int ni = 0; ni < 4; ++ni) {
        const int rt = wn * 64 + ni * 16 + lr;
        boff[ni] = rt * 64 + (lq ^ (rt & 3)) * 16;
    }

    f32x4 acc[4][4];
    #pragma unroll
    for (int mi = 0; mi < 4; ++mi)
        #pragma unroll
        for (int ni = 0; ni < 4; ++ni)
            acc[mi][ni] = (f32x4){0.f, 0.f, 0.f, 0.f};

    STAGE(0, 0);
    for (int t = 0; t < NT; ++t) {
        const int cur = t & 1;
        if (t + 1 < NT) {
            STAGE(t + 1, cur ^ 1);                         // stays in flight across barrier
            asm volatile("s_waitcnt vmcnt(4)" ::: "memory");   // tile t's 4 loads done
        } else {
            asm volatile("s_waitcnt vmcnt(0)" ::: "memory");
        }
        __builtin_amdgcn_sched_barrier(0);
        __builtin_amdgcn_s_barrier();                      // all waves' tile-t DMA visible
        __builtin_amdgcn_sched_barrier(0);

        short8 af[4], bfr[4];
        #pragma unroll
        for (int mi = 0; mi < 4; ++mi) {
            const float4 lo = *(const float4*)&Ab[cur][aoff0[mi]];
            const float4 hi = *(const float4*)&Ab[cur][aoff1[mi]];
            short8 a8;
            a8[0] = cvt1(lo.x); a8[1] = cvt1(lo.y); a8[2] = cvt1(lo.z); a8[3] = cvt1(lo.w);
            a8[4] = cvt1(hi.x); a8[5] = cvt1(hi.y); a8[6] = cvt1(hi.z); a8[7] = cvt1(hi.w);
            af[mi] = a8;
        }
        #pragma unroll
        for (int ni = 0; ni < 4; ++ni)
            bfr[ni] = *(const short8*)&Bb[cur][boff[ni]];
        #pragma unroll
        for (int mi = 0; mi < 4; ++mi)
            #pragma unroll
            for (int ni = 0; ni < 4; ++ni)
                acc[mi][ni] = __builtin_amdgcn_mfma_f32_16x16x32_bf16(
                    af[mi], bfr[ni], acc[mi][ni], 0, 0, 0);

        __builtin_amdgcn_sched_barrier(0);
        __builtin_amdgcn_s_barrier();                      // buf[cur] free for overwrite
        __builtin_amdgcn_sched_barrier(0);
    }
#undef STAGE

    // ---- fused trace epilogue: weight acc rows by o[a][row], reduce ----
    // acc[mi][ni][j]: row = rb*128 + wm*64 + mi*16 + lq*4 + j, time = wn*64 + ni*16 + lr
    float* plds = (float*)&Ab[0][0];   // 2 x 256 floats (LDS free after last barrier)

    #pragma unroll
    for (int ni = 0; ni < 4; ++ni) {
        const int a_idx = wn * 64 + ni * 16 + lr;
        float ps = 0.f;
        #pragma unroll
        for (int mi = 0; mi < 4; ++mi) {
            const int bg = rb * 128 + wm * 64 + mi * 16 + lq * 4;
            const ushort4 w = *(const ushort4*)(obf + (size_t)a_idx * DDIM + bg);
            ps += bf2f(w.x) * acc[mi][ni][0];
            ps += bf2f(w.y) * acc[mi][ni][1];
            ps += bf2f(w.z) * acc[mi][ni][2];
            ps += bf2f(w.w) * acc[mi][ni][3];
        }
        ps += __shfl_xor(ps, 16);
        ps += __shfl_xor(ps, 32);
        if (lane < 16) plds[wm * 256 + a_idx] = ps;
    }
    __syncthreads();
    if (tid < 256)
        part[((size_t)d * 16 + rb) * TTIMES + tid] = plds[tid] + plds[256 + tid];
}

// ---------------- final reduce over row-blocks ----------------
__global__ void reduce_part(const float* __restrict__ part, float* __restrict__ out) {
    const int d = blockIdx.x;    // 32
    const int a = threadIdx.x;   // 256
    float s = 0.f;
    #pragma unroll
    for (int rb = 0; rb < 16; ++rb)
        s += part[((size_t)d * 16 + rb) * TTIMES + a];
    out[(size_t)d * TTIMES + a] = s;
}

extern "C" void kernel_launch(void* const* d_in, const int* in_sizes, int n_in,
                              void* d_out, int out_size, void* d_ws, size_t ws_size,
                              hipStream_t stream) {
    const float* x   = (const float*)d_in[0];   // (32, 2048, 2048) fp32
    const float* org = (const float*)d_in[1];   // (256, 2048) fp32
    float* out = (float*)d_out;                 // (32, 256) fp32

    ushort* obf = (ushort*)d_ws;                          // 1 MiB bf16 normalized o
    float*  prt = (float*)((char*)d_ws + (1 << 20));      // 512 KiB partials (32x16x256)

    norm_rows<<<dim3(TTIMES), dim3(256), 0, stream>>>(org, obf);
    gemm_trace<<<dim3(16, 32), dim3(THREADS), 0, stream>>>(x, obf, prt);
    reduce_part<<<dim3(32), dim3(256), 0, stream>>>(prt, out);
}